// Round 1
// baseline (220.972 us; speedup 1.0000x reference)
//
#include <hip/hip_runtime.h>
#include <hip/hip_bf16.h>
#include <stdint.h>

#define B_  64
#define N_  576
#define D_  1024
#define K_  144
#define HW_ 24
#define DIST_THR_F 16.733200530681511f

using bf16x8 = __attribute__((ext_vector_type(8))) short;
using f32x4  = __attribute__((ext_vector_type(4))) float;

__device__ __forceinline__ unsigned short f2bf(float f) {
    unsigned u = __float_as_uint(f);
    u += 0x7fffu + ((u >> 16) & 1u);
    return (unsigned short)(u >> 16);
}

// ---------------- Kernel 1: row L2-normalize hs_sim and cast to bf16 ----------------
// one wave per row of 1024 f32; 4 rows per 256-thread block
__global__ __launch_bounds__(256) void k_normcast(const float* __restrict__ x,
                                                  unsigned short* __restrict__ pn) {
    int row  = blockIdx.x * 4 + (threadIdx.x >> 6);
    int lane = threadIdx.x & 63;
    const float4* src = reinterpret_cast<const float4*>(x + (size_t)row * D_);
    float4 v[4];
    float ss = 0.f;
#pragma unroll
    for (int q = 0; q < 4; q++) {
        v[q] = src[lane + 64 * q];
        ss += v[q].x * v[q].x + v[q].y * v[q].y + v[q].z * v[q].z + v[q].w * v[q].w;
    }
#pragma unroll
    for (int m = 32; m >= 1; m >>= 1) ss += __shfl_xor(ss, m, 64);
    float inv = 1.0f / fmaxf(sqrtf(ss), 1e-12f);
    ushort4* dst = reinterpret_cast<ushort4*>(pn + (size_t)row * D_);
#pragma unroll
    for (int q = 0; q < 4; q++) {
        ushort4 o;
        o.x = f2bf(v[q].x * inv); o.y = f2bf(v[q].y * inv);
        o.z = f2bf(v[q].z * inv); o.w = f2bf(v[q].w * inv);
        dst[lane + 64 * q] = o;
    }
}

// ---------------- Kernel 2: token selection (one block per batch) ----------------
__global__ __launch_bounds__(256) void k_select(const float* __restrict__ metric,
                                                int* __restrict__ bench_idx,
                                                int* __restrict__ high,
                                                float* __restrict__ out_idx) {
    __shared__ float sm[N_];
    __shared__ float sc[512];
    __shared__ int   si[512];
    __shared__ unsigned smask[18];
    __shared__ int   wpref[18];
    __shared__ float thr_s;
    int b = blockIdx.x, tid = threadIdx.x;
    for (int i = tid; i < N_; i += 256) sm[i] = metric[b * N_ + i];
    if (tid < 18) smask[tid] = 0u;
    __syncthreads();
    // per-2x2-region top-2 candidates (144 regions -> 288 candidates)
    if (tid < 144) {
        int ry = tid / 12, rx = tid - ry * 12;
        int base = ry * 48 + rx * 2;            // (2*ry)*24 + 2*rx
        float vv[4] = { sm[base], sm[base + 1], sm[base + 24], sm[base + 25] };
        int   tk[4] = { base, base + 1, base + 24, base + 25 };
        int a0 = 0;
#pragma unroll
        for (int j = 1; j < 4; j++) if (vv[j] > vv[a0]) a0 = j;
        int a1 = -1;
#pragma unroll
        for (int j = 0; j < 4; j++) {
            if (j == a0) continue;
            if (a1 < 0 || vv[j] > vv[a1]) a1 = j;
        }
        sc[2 * tid]     = vv[a0]; si[2 * tid]     = tk[a0];
        sc[2 * tid + 1] = vv[a1]; si[2 * tid + 1] = tk[a1];
    }
    for (int i = 288 + tid; i < 512; i += 256) { sc[i] = -1e30f; si[i] = 0x7fffffff; }
    __syncthreads();
    // bitonic sort 512, descending by score (idx ascending as tiebreak)
    for (int k = 2; k <= 512; k <<= 1) {
        for (int j = k >> 1; j > 0; j >>= 1) {
#pragma unroll 2
            for (int t = tid; t < 512; t += 256) {
                int ixj = t ^ j;
                if (ixj > t) {
                    float s1 = sc[t], s2 = sc[ixj];
                    int   i1 = si[t], i2 = si[ixj];
                    bool before = (s1 > s2) || (s1 == s2 && i1 < i2);
                    bool up = ((t & k) == 0);
                    if (up ? !before : before) {
                        sc[t] = s2; sc[ixj] = s1; si[t] = i2; si[ixj] = i1;
                    }
                }
            }
            __syncthreads();
        }
    }
    // quantile threshold: q*(K-1) = 78.65 -> lerp between ascending s[78]=desc[65], s[79]=desc[64]
    if (tid == 0) {
        float qpos = 0.55f * 143.0f;
        float g = qpos - 78.0f;
        thr_s = sc[65] * (1.0f - g) + sc[64] * g;
    }
    if (tid < 144) atomicOr(&smask[si[tid] >> 5], 1u << (si[tid] & 31));
    __syncthreads();
    if (tid == 0) {
        int acc = 0;
        for (int w = 0; w < 18; w++) { wpref[w] = acc; acc += __popc(smask[w]); }
    }
    __syncthreads();
    if (tid < 144) {
        int tok = si[tid], w = tok >> 5;
        int rank = wpref[w] + __popc(smask[w] & ((1u << (tok & 31)) - 1u));
        bench_idx[b * K_ + rank] = tok;
        high[b * K_ + rank] = (sc[tid] >= thr_s) ? 1 : 0;
        out_idx[b * K_ + rank] = (float)tok;
    }
}

// ---------------- Kernel 3: sim rows GEMM + relu*penalty -> bwn (bf16, unnormalized) ----
// wave tile 48(bench) x 48(tokens); K-loop over D=1024; mfma 16x16x32 bf16
__global__ __launch_bounds__(256) void k_sim(const unsigned short* __restrict__ pn,
                                             const int* __restrict__ bench_idx,
                                             unsigned short* __restrict__ bwn) {
    int wid  = blockIdx.x * 4 + (threadIdx.x >> 6);
    int lane = threadIdx.x & 63;
    int jt  = wid % 12;
    int rem = wid / 12;
    int it  = rem % 3;
    int b   = rem / 3;
    int g = lane >> 4, r16 = lane & 15;
    const unsigned short* pnb = pn + (size_t)b * N_ * D_;
    int tokA[3];
#pragma unroll
    for (int s = 0; s < 3; s++)
        tokA[s] = bench_idx[b * K_ + it * 48 + s * 16 + r16];
    f32x4 acc[3][3] = {};
    for (int kk = 0; kk < D_; kk += 32) {
        bf16x8 af[3], bfr[3];
#pragma unroll
        for (int s = 0; s < 3; s++)
            af[s] = *reinterpret_cast<const bf16x8*>(pnb + (size_t)tokA[s] * D_ + kk + g * 8);
#pragma unroll
        for (int s = 0; s < 3; s++)
            bfr[s] = *reinterpret_cast<const bf16x8*>(pnb + (size_t)(jt * 48 + s * 16 + r16) * D_ + kk + g * 8);
#pragma unroll
        for (int mi = 0; mi < 3; mi++)
#pragma unroll
            for (int nj = 0; nj < 3; nj++)
                acc[mi][nj] = __builtin_amdgcn_mfma_f32_16x16x32_bf16(af[mi], bfr[nj], acc[mi][nj], 0, 0, 0);
    }
    // epilogue: C row = (lane>>4)*4 + reg, col = lane&15 (within each 16x16 tile)
#pragma unroll
    for (int mi = 0; mi < 3; mi++) {
#pragma unroll
        for (int r = 0; r < 4; r++) {
            int slot = it * 48 + mi * 16 + g * 4 + r;
            int ti = bench_idx[b * K_ + slot];
            int y1 = ti / HW_, x1 = ti % HW_;
            unsigned short* prow = bwn + (size_t)(b * K_ + slot) * N_;
#pragma unroll
            for (int nj = 0; nj < 3; nj++) {
                int jg = jt * 48 + nj * 16 + r16;
                int y2 = jg / HW_, x2 = jg % HW_;
                float dy = (float)(y1 - y2), dx = (float)(x1 - x2);
                float dist = sqrtf(dy * dy + dx * dx);
                float pen = 1.0f - fminf(dist / DIST_THR_F, 1.0f);
                float val = fmaxf(acc[mi][nj][r], 0.0f) * pen;
                prow[jg] = f2bf(val);
            }
        }
    }
}

// ---------------- Kernel 4: per-row normalize (in place, bf16); high rows -> one-hot ----
__global__ __launch_bounds__(256) void k_norm(unsigned short* __restrict__ bwn,
                                              const int* __restrict__ bench_idx,
                                              const int* __restrict__ high) {
    int row  = blockIdx.x * 4 + (threadIdx.x >> 6);
    int lane = threadIdx.x & 63;
    int tok = bench_idx[row];
    int hi  = high[row];
    unsigned short* pr = bwn + (size_t)row * N_;
    if (hi) {
#pragma unroll
        for (int q = 0; q < 9; q++) {
            int j = lane + 64 * q;
            pr[j] = (j == tok) ? (unsigned short)0x3F80 : (unsigned short)0;
        }
    } else {
        float v[9];
        float s = 0.f;
#pragma unroll
        for (int q = 0; q < 9; q++) {
            v[q] = __uint_as_float((unsigned)pr[lane + 64 * q] << 16);
            s += v[q];
        }
#pragma unroll
        for (int m = 32; m >= 1; m >>= 1) s += __shfl_xor(s, m, 64);
        float scale = 1.0f / (s + 1e-8f);
#pragma unroll
        for (int q = 0; q < 9; q++) {
            int j = lane + 64 * q;
            pr[j] = (j == tok) ? (unsigned short)0x3F80 : f2bf(v[q] * scale);
        }
    }
}

// ---------------- Kernel 5: transpose+cast agg -> aggT[d][j] bf16 (per 64x64 tile) ------
__global__ __launch_bounds__(256) void k_transpose(const float* __restrict__ agg,
                                                   unsigned short* __restrict__ aggT) {
    __shared__ unsigned short lds[64][68];   // pad 4 to spread banks
    int blk = blockIdx.x;
    int jt  = blk % 9;
    int rem = blk / 9;
    int dt  = rem % 16;
    int b   = rem / 16;
    int tid = threadIdx.x;
    const float* src = agg + (size_t)b * N_ * D_;
#pragma unroll
    for (int q = 0; q < 4; q++) {
        int f  = tid + 256 * q;     // float4 index within 64x64 tile
        int j  = f >> 4;            // 0..63
        int d4 = f & 15;            // 0..15
        float4 v = *reinterpret_cast<const float4*>(src + (size_t)(jt * 64 + j) * D_ + dt * 64 + d4 * 4);
        lds[j][d4 * 4 + 0] = f2bf(v.x);
        lds[j][d4 * 4 + 1] = f2bf(v.y);
        lds[j][d4 * 4 + 2] = f2bf(v.z);
        lds[j][d4 * 4 + 3] = f2bf(v.w);
    }
    __syncthreads();
    unsigned short* dst = aggT + (size_t)b * D_ * N_;
#pragma unroll
    for (int q = 0; q < 4; q++) {
        int o  = tid + 256 * q;
        int d  = o >> 4;            // 0..63
        int j4 = (o & 15) * 4;      // 0..60
        ushort4 t;
        t.x = lds[j4 + 0][d]; t.y = lds[j4 + 1][d];
        t.z = lds[j4 + 2][d]; t.w = lds[j4 + 3][d];
        *reinterpret_cast<ushort4*>(dst + (size_t)(dt * 64 + d) * N_ + jt * 64 + j4) = t;
    }
}

// ---------------- Kernel 6: aggregation GEMM: out[b,i,d] = sum_j bwn[i,j]*agg[b,j,d] ----
// wave tile 48(rows) x 64(d); K-loop over N=576
__global__ __launch_bounds__(256) void k_agg(const unsigned short* __restrict__ bwn,
                                             const unsigned short* __restrict__ aggT,
                                             float* __restrict__ out) {
    int wid  = blockIdx.x * 4 + (threadIdx.x >> 6);
    int lane = threadIdx.x & 63;
    int dt  = wid % 16;
    int rem = wid / 16;
    int it  = rem % 3;
    int b   = rem / 3;
    int g = lane >> 4, r16 = lane & 15;
    const unsigned short* wrow = bwn  + (size_t)b * K_ * N_;
    const unsigned short* at   = aggT + (size_t)b * D_ * N_;
    f32x4 acc[3][4] = {};
    for (int kk = 0; kk < N_; kk += 32) {
        bf16x8 af[3], bfr[4];
#pragma unroll
        for (int s = 0; s < 3; s++)
            af[s] = *reinterpret_cast<const bf16x8*>(wrow + (size_t)(it * 48 + s * 16 + r16) * N_ + kk + g * 8);
#pragma unroll
        for (int s = 0; s < 4; s++)
            bfr[s] = *reinterpret_cast<const bf16x8*>(at + (size_t)(dt * 64 + s * 16 + r16) * N_ + kk + g * 8);
#pragma unroll
        for (int mi = 0; mi < 3; mi++)
#pragma unroll
            for (int nj = 0; nj < 4; nj++)
                acc[mi][nj] = __builtin_amdgcn_mfma_f32_16x16x32_bf16(af[mi], bfr[nj], acc[mi][nj], 0, 0, 0);
    }
#pragma unroll
    for (int mi = 0; mi < 3; mi++) {
#pragma unroll
        for (int r = 0; r < 4; r++) {
            int i = it * 48 + mi * 16 + g * 4 + r;
            float* orow = out + (size_t)(b * K_ + i) * D_ + dt * 64;
#pragma unroll
            for (int nj = 0; nj < 4; nj++)
                orow[nj * 16 + r16] = acc[mi][nj][r];
        }
    }
}

extern "C" void kernel_launch(void* const* d_in, const int* in_sizes, int n_in,
                              void* d_out, int out_size, void* d_ws, size_t ws_size,
                              hipStream_t stream) {
    const float* hs_agg = (const float*)d_in[0];
    const float* hs_sim = (const float*)d_in[1];
    const float* metric = (const float*)d_in[2];
    float* out = (float*)d_out;
    char* ws = (char*)d_ws;

    // ws layout: [pn bf16 | aggT bf16 (reuses pn region)] [bwn bf16] [bench_idx] [high]
    const size_t PN_BYTES  = (size_t)B_ * N_ * D_ * 2;    // 75,497,472 (also holds aggT)
    const size_t BWN_BYTES = (size_t)B_ * K_ * N_ * 2;    // 10,616,832
    unsigned short* pn   = (unsigned short*)ws;
    unsigned short* bwn  = (unsigned short*)(ws + PN_BYTES);
    int* bench_idx = (int*)(ws + PN_BYTES + BWN_BYTES);
    int* high      = (int*)(ws + PN_BYTES + BWN_BYTES + (size_t)B_ * K_ * 4);
    float* out_idx = out + (size_t)B_ * K_ * D_;

    hipLaunchKernelGGL(k_normcast,  dim3((B_ * N_) / 4), dim3(256), 0, stream, hs_sim, pn);
    hipLaunchKernelGGL(k_select,    dim3(B_),            dim3(256), 0, stream, metric, bench_idx, high, out_idx);
    hipLaunchKernelGGL(k_sim,       dim3(B_ * 3 * 12 / 4), dim3(256), 0, stream, pn, bench_idx, bwn);
    hipLaunchKernelGGL(k_norm,      dim3((B_ * K_) / 4), dim3(256), 0, stream, bwn, bench_idx, high);
    hipLaunchKernelGGL(k_transpose, dim3(B_ * 16 * 9),   dim3(256), 0, stream, hs_agg, pn);
    hipLaunchKernelGGL(k_agg,       dim3(B_ * 3 * 16 / 4), dim3(256), 0, stream, bwn, pn, out);
}